// Round 12
// baseline (111.566 us; speedup 1.0000x reference)
//
#include <hip/hip_runtime.h>
#include <stdint.h>

typedef float v4f __attribute__((ext_vector_type(4)));
typedef int   v8i __attribute__((ext_vector_type(8)));
typedef unsigned long long u64;

#define PEX_STRIDE 1156
#define WS_IMG8   0
#define WS_BFRAG  1048576
#define WS_PEX    1064960
#define WS_RESULT 9994240
#define WS_CAND   14188544

__device__ inline unsigned char f32_to_e4m3(float v) {
    if (!(v > 0.0f)) return 0;
    if (v >= 448.0f) return 0x7e;
    if (v < 0.015625f) {                       // subnormal: m * 2^-9
        int m = (int)(v * 512.0f + 0.5f);
        if (m > 7) return 0x08;
        return (unsigned char)m;
    }
    unsigned int u = __float_as_uint(v) + 0x00080000u;  // round into bit 20
    int e = (int)((u >> 23) & 0xff) - 127;
    int m3 = (int)(u >> 20) & 7;
    int e8 = e + 7;
    if (e8 >= 16) return 0x7e;
    return (unsigned char)((e8 << 3) | m3);
}

// Fused front kernel.
// blocks [0,1024): wrapped row prefix sums + fp8 image emit (row L1-hot)
// blocks [1024,2080): zero d_out
// blocks [2080,2144): A-fragment psf table for the K=128 MX MFMA:
//   abuf[kb4][lane][b] fp8 = psf[z][a][b]*cos(2pi(a+b-32)/1024)*1024,
//   z=lane&15, a=4*kb4+(lane>>4), b=0..31; also zeroes cnt[0].
__global__ void k_pex(const float* __restrict__ img, float* __restrict__ pex,
                      uint32_t* __restrict__ img8, const float* __restrict__ psf,
                      unsigned char* __restrict__ bf, unsigned int* cnt,
                      float4* __restrict__ out, int n4) {
    __shared__ float wtot[4];
    int blk = blockIdx.x, t = threadIdx.x;
    if (blk >= 1024) {
        if (blk < 2080) {
            int i = (blk - 1024) * 256 + t;
            if (i < n4) { float4 z; z.x = z.y = z.z = z.w = 0.f; out[i] = z; }
        } else {
            int u = (blk - 2080) * 256 + t;   // 16384 = 8 kb4 x 64 lanes x 32 B
            if (u == 0) cnt[0] = 0u;
            int kb4 = u >> 11; int l = (u >> 5) & 63; int b = u & 31;
            int z = l & 15; int a = kb4 * 4 + (l >> 4);
            float p = psf[z * 1024 + a * 32 + b];
            float c = cosf((float)(a + b - 32) * (6.283185307179586f / 1024.0f));
            bf[u] = f32_to_e4m3(p * c * 1024.0f);
        }
        return;
    }
    int r = blk;
    const float* row = img + r * 1024;
    float s[5];
    float acc = 0.f;
    int base = t * 5;
    #pragma unroll
    for (int j = 0; j < 5; j++) {
        int c = base + j;
        float v = (c < 1152) ? row[(c - 64) & 1023] : 0.f;
        acc += v; s[j] = acc;
    }
    float sc = acc;
    int lane = t & 63, w = t >> 6;
    #pragma unroll
    for (int off = 1; off < 64; off <<= 1) {
        float v = __shfl_up(sc, off, 64);
        if (lane >= off) sc += v;
    }
    if (lane == 63) wtot[w] = sc;
    __syncthreads();
    float wbase = 0.f;
    #pragma unroll
    for (int i = 0; i < 3; i++) if (i < w) wbase += wtot[i];
    float excl = wbase + (sc - acc);
    float* prow = pex + r * PEX_STRIDE;
    if (t == 0) prow[0] = 0.f;
    #pragma unroll
    for (int j = 0; j < 5; j++) {
        int c = base + j;
        if (c < 1152) prow[c + 1] = excl + s[j];
    }
    float4 v4 = *(const float4*)(row + 4 * t);
    img8[r * 256 + t] = (uint32_t)f32_to_e4m3(v4.x)
                      | ((uint32_t)f32_to_e4m3(v4.y) << 8)
                      | ((uint32_t)f32_to_e4m3(v4.z) << 16)
                      | ((uint32_t)f32_to_e4m3(v4.w) << 24);
}

// build MX MFMA B operand from 4 u64 (constant-index inserts: register-only)
__device__ inline v8i packb(u64 a, u64 b, u64 c, u64 d) {
    v8i v;
    v[0] = (int)(unsigned int)a;  v[1] = (int)(unsigned int)(a >> 32);
    v[2] = (int)(unsigned int)b;  v[3] = (int)(unsigned int)(b >> 32);
    v[4] = (int)(unsigned int)c;  v[5] = (int)(unsigned int)(c >> 32);
    v[6] = (int)(unsigned int)d;  v[7] = (int)(unsigned int)(d >> 32);
    return v;
}

__device__ inline float redz(v4f a) {   // z-max over 16 z (4 regs + cross-g)
    float m = fmaxf(fmaxf(a.x, a.y), fmaxf(a.z, a.w));
    m = fmaxf(m, __shfl_xor(m, 16, 64));
    m = fmaxf(m, __shfl_xor(m, 32, 64));
    return m;
}

// MFMA conv (MX fp8 K=128): single-copy LDS staging + register funnel shifts.
// r10 PMC: 8-copy LDS staging = ~15K b64 LDS ops/block (LDS-pipe bound, 30us).
// r11 PMC: zero-LDS variant rematerialized uncoalesced global loads (VGPR
// clamp 128, FETCH 25MB, 48us). This round: stage tile ONCE into LDS (760
// coalesced u64 writes), per-lane 6-u64 windows via b128 reads (10-u64 row
// stride: lane bank-start 20*(nn+g) mod 32 tiles all banks -> conflict-free),
// byte-shifts as register funnels. 8 waves = 4 rowgrps x 2 chain-halves;
// per wave: 16 accs (64 VGPR), window 12 VGPR per kb4 step, 5 funnels ->
// 2 MFMAs per (sh,kb4), 128 MFMAs total. ~110 VGPR -> 4 waves/SIMD.
__global__ __launch_bounds__(512, 4) void k_conv(
    const unsigned long long* __restrict__ img64,
    const unsigned char* __restrict__ bfrag,
    const float* __restrict__ pex, float* __restrict__ result) {
    __shared__ ulonglong2 smv[95 * 5];     // [row][5x16B]; u64 0..7 used, 8..9 pad
    __shared__ float rbp[8][5][8];
    __shared__ float rbv[8][5];
    int tid = threadIdx.x;
    int wave = tid >> 6, lane = tid & 63;
    int b = blockIdx.x;
    int tr = b >> 5, tc = b & 31;
    int r0 = tr * 64, c0 = tc * 32;

    // fused bg partial sums (disk r=64 mean via pex prefix): 8x8 rows x 5
    // sampled cols = 40 lanes, dy-chunk of 16 per wave; j==127 predicated off.
    if (lane < 40) {
        int si = lane / 5, kc = lane - si * 5;
        int baserow = r0 + si * 8 + 3;
        int n = c0 + 8 * kc;
        int j0 = wave * 16;
        float acc = 0.f;
        #pragma unroll
        for (int u = 0; u < 16; u++) {
            int j = j0 + u;
            if (j < 127) {
                int dy = j - 63;
                int ady = dy < 0 ? -dy : dy;
                int w = (int)sqrtf((float)(4095 - ady * ady));
                const float* p = pex + ((baserow + dy) & 1023) * PEX_STRIDE + n;
                acc += p[65 + w] - p[64 - w];
            }
        }
        rbp[si][kc][wave] = acc;
    }

    // staging: 95 rows x 8 u64 (single copy — no shifted expansion)
    u64* smq = (u64*)smv;
    for (int u = tid; u < 760; u += 512) {
        int dr = u >> 3, j = u & 7;
        int row = (r0 + dr - 16) & 1023;
        int cbyte = (c0 - 16 + 8 * j) & 1023;
        smq[dr * 10 + j] = img64[row * 128 + (cbyte >> 3)];
    }
    __syncthreads();
    if (tid < 40) {
        int si = tid / 5, kc = tid - si * 5;
        float s = 0.f;
        #pragma unroll
        for (int h = 0; h < 8; h++) s += rbp[si][kc][h];
        const float kk = (float)(1.0 / (3.14159265358979323846 * 4096.0));
        rbv[si][kc] = 1.0f / ((s * kk + 1.0f) * 1024.0f);  // /1024 undoes psf scale
    }

    int rg = wave >> 1, h = wave & 1;         // row group, chain half
    int i0 = rg * 16;
    int nn = lane & 15, g = lane >> 4;
    const v8i* bfA = (const v8i*)(bfrag + lane * 32);   // A rows for this lane

    v4f acc0[8], acc1[8];                     // [sh] chains 2h, 2h+1
    #pragma unroll
    for (int s = 0; s < 8; s++) { acc0[s] = (v4f)0.f; acc1[s] = (v4f)0.f; }

    #pragma unroll
    for (int kb4 = 0; kb4 < 8; kb4++) {
        int lr = i0 + nn + g + 4 * kb4;       // local staged row 0..94
        const ulonglong2* rp = smv + lr * 5 + h;
        ulonglong2 p0 = rp[0], p1 = rp[1], p2 = rp[2];
        u64 w0 = p0.x, w1 = p0.y, w2 = p1.x, w3 = p1.y, w4 = p2.x, w5 = p2.y;
        v8i av = bfA[kb4 << 6];               // bfrag + kb4*2048 + lane*32
        #pragma unroll
        for (int sh = 0; sh < 8; sh++) {
            u64 S0, S1, S2, S3, S4;
            if (sh == 0) { S0 = w0; S1 = w1; S2 = w2; S3 = w3; S4 = w4; }
            else {
                const int sb = 8 * sh;
                S0 = (w0 >> sb) | (w1 << (64 - sb));
                S1 = (w1 >> sb) | (w2 << (64 - sb));
                S2 = (w2 >> sb) | (w3 << (64 - sb));
                S3 = (w3 >> sb) | (w4 << (64 - sb));
                S4 = (w4 >> sb) | (w5 << (64 - sb));
            }
            acc0[sh] = __builtin_amdgcn_mfma_scale_f32_16x16x128_f8f6f4(
                    av, packb(S0, S1, S2, S3), acc0[sh], 0, 0, 0,
                    0x7f7f7f7f, 0, 0x7f7f7f7f);
            acc1[sh] = __builtin_amdgcn_mfma_scale_f32_16x16x128_f8f6f4(
                    av, packb(S1, S2, S3, S4), acc1[sh], 0, 0, 0,
                    0x7f7f7f7f, 0, 0x7f7f7f7f);
        }
    }

    float zm0[8], zm1[8];
    #pragma unroll
    for (int sh = 0; sh < 8; sh++) { zm0[sh] = redz(acc0[sh]); zm1[sh] = redz(acc1[sh]); }
    __syncthreads();   // rbv ready

    // epilogue: lane (nn,g) stores row i0+nn, cols c0+16h+4g..+3 (16B float4)
    int sil = (i0 + nn) >> 3;
    int kc = 2 * h + (g >> 1);
    float rv0 = rbv[sil][kc], rv1 = rbv[sil][kc + 1];
    float drv = rv1 - rv0;
    float ov[4];
    #pragma unroll
    for (int t = 0; t < 4; t++) {
        float za = (g & 1) ? zm0[4 + t] : zm0[t];
        float zb = (g & 1) ? zm1[4 + t] : zm1[t];
        float z = (g & 2) ? zb : za;
        float fr = (float)(4 * (g & 1) + t) * 0.125f;
        ov[t] = z * (rv0 + fr * drv);
    }
    float4 o; o.x = ov[0]; o.y = ov[1]; o.z = ov[2]; o.w = ov[3];
    *(float4*)(result + (r0 + i0 + nn) * 1024 + c0 + 16 * h + 4 * g) = o;
}

// fused 32x32 stride-1 maxpool + candidate extraction, with fast reject.
__global__ __launch_bounds__(256) void k_maxcand(const float* __restrict__ result,
                                                 unsigned int* cnt,
                                                 unsigned long long* cand) {
    __shared__ float ls[95 * 96];
    __shared__ float hr[95 * 64];
    __shared__ float wmax[4];
    int bx = blockIdx.x & 15, by = blockIdx.x >> 4;
    int i0 = by * 64, j0 = bx * 64;
    int t = threadIdx.x;
    // fast reject: tile max over the 64x64 core (float4 loads)
    const float4* cb4 = (const float4*)(result + i0 * 1024 + j0);
    float mx = -3.4e38f;
    #pragma unroll
    for (int k = 0; k < 4; k++) {
        int idx = k * 256 + t;                 // 1024 float4: row idx>>4, col4 idx&15
        float4 v = cb4[(idx >> 4) * 256 + (idx & 15)];
        mx = fmaxf(mx, fmaxf(fmaxf(v.x, v.y), fmaxf(v.z, v.w)));
    }
    #pragma unroll
    for (int m = 1; m < 64; m <<= 1) mx = fmaxf(mx, __shfl_xor(mx, m, 64));
    if ((t & 63) == 0) wmax[t >> 6] = mx;
    __syncthreads();
    float tmax = fmaxf(fmaxf(wmax[0], wmax[1]), fmaxf(wmax[2], wmax[3]));
    if (tmax <= 2.0f) return;

    // slow path: full separable pooling on the 95x95 halo
    for (int idx = t; idx < 95 * 95; idx += 256) {
        int r = idx / 95, c = idx - r * 95;
        int gr = i0 - 16 + r, gc = j0 - 16 + c;
        float v = -3.4e38f;
        if ((unsigned)gr < 1024u && (unsigned)gc < 1024u) v = result[gr * 1024 + gc];
        ls[r * 96 + c] = v;
    }
    __syncthreads();
    for (int idx = t; idx < 95 * 64; idx += 256) {
        int r = idx >> 6, c = idx & 63;
        const float* p = ls + r * 96 + c;
        float m = p[0];
        #pragma unroll
        for (int d = 1; d < 32; d++) m = fmaxf(m, p[d]);
        hr[idx] = m;
    }
    __syncthreads();
    for (int idx = t; idx < 64 * 64; idx += 256) {
        int r = idx >> 6, c = idx & 63;
        const float* p = hr + r * 64 + c;
        float m = p[0];
        #pragma unroll
        for (int d = 1; d < 32; d++) m = fmaxf(m, p[d * 64]);
        float v = ls[(r + 16) * 96 + (c + 16)];
        int gi = i0 + r, gj = j0 + c;
        if (gi >= 1 && gj >= 1 && v > 2.0f && v == m) {
            unsigned int k = atomicAdd(cnt, 1u);
            if (k < 2048)
                cand[k] = ((unsigned long long)__float_as_uint(v) << 32)
                        | (unsigned int)(~(unsigned int)(gi * 1024 + gj));
        }
    }
}

// sort candidates (value desc, index asc) and emit outputs; empty fast path
__global__ __launch_bounds__(1024) void k_final(
    const float* __restrict__ image, const unsigned int* __restrict__ cnt,
    const unsigned long long* __restrict__ cand, float* __restrict__ out) {
    __shared__ unsigned long long keys[2048];
    int t = threadIdx.x;
    int n = (int)cnt[0]; if (n > 2048) n = 2048;
    if (n == 0) return;                         // d_out already zeroed by k_pex
    for (int k = t; k < 2048; k += 1024) keys[k] = (k < n) ? cand[k] : 0ull;
    __syncthreads();
    for (int size = 2; size <= 2048; size <<= 1) {
        for (int stride = size >> 1; stride > 0; stride >>= 1) {
            for (int i = t; i < 2048; i += 1024) {
                int ixj = i ^ stride;
                if (ixj > i) {
                    unsigned long long a = keys[i], b = keys[ixj];
                    bool sw = ((i & size) == 0) ? (a < b) : (a > b);  // descending
                    if (sw) { keys[i] = b; keys[ixj] = a; }
                }
            }
            __syncthreads();
        }
    }
    float* roipos = out;
    float* intensity = out + 2048;
    float* rois = out + 3072;
    float* validf = out + 3072 + 1048576;
    int nw = n < 1024 ? n : 1024;
    if (t < nw) {
        unsigned long long key = keys[t];
        float val = __uint_as_float((unsigned int)(key >> 32));
        unsigned int p = ~(unsigned int)key;
        int y = (int)(p >> 10), x = (int)(p & 1023);
        int roy = y - 16, rox = x - 16;
        bool valid = (roy >= 0 && roy < 992 && rox >= 0 && rox < 992);
        int royc = roy < 0 ? 0 : (roy > 992 ? 992 : roy);
        int roxc = rox < 0 ? 0 : (rox > 992 ? 992 : rox);
        roipos[2 * t]     = valid ? (float)royc : 0.f;
        roipos[2 * t + 1] = valid ? (float)roxc : 0.f;
        intensity[t]      = valid ? val : 0.f;
        validf[t]         = valid ? 1.f : 0.f;
    }
    __syncthreads();
    for (int k = 0; k < nw; k++) {
        unsigned long long key = keys[k];
        unsigned int p = ~(unsigned int)key;
        int y = (int)(p >> 10), x = (int)(p & 1023);
        int roy = y - 16, rox = x - 16;
        if (!(roy >= 0 && roy < 992 && rox >= 0 && rox < 992)) continue;
        int u = t >> 5, vv = t & 31;
        rois[k * 1024 + t] = image[(roy + u) * 1024 + (rox + vv)];
    }
}

extern "C" void kernel_launch(void* const* d_in, const int* in_sizes, int n_in,
                              void* d_out, int out_size, void* d_ws, size_t ws_size,
                              hipStream_t stream) {
    const float* image = (const float*)d_in[0];
    const float* psf   = (const float*)d_in[1];
    float* out = (float*)d_out;
    char* ws = (char*)d_ws;
    unsigned char* img8  = (unsigned char*)(ws + WS_IMG8);
    unsigned char* bfrag = (unsigned char*)(ws + WS_BFRAG);
    float* pex = (float*)(ws + WS_PEX);
    float* result = (float*)(ws + WS_RESULT);
    unsigned int* cnt = (unsigned int*)(ws + WS_CAND);
    unsigned long long* cand = (unsigned long long*)(ws + WS_CAND + 16);

    int n4 = out_size / 4;
    hipLaunchKernelGGL(k_pex,     dim3(2144), dim3(256), 0, stream,
                       image, pex, (uint32_t*)img8, psf, bfrag, cnt, (float4*)d_out, n4);
    hipLaunchKernelGGL(k_conv,    dim3(512),  dim3(512), 0, stream,
                       (const unsigned long long*)img8, bfrag, pex, result);
    hipLaunchKernelGGL(k_maxcand, dim3(256),  dim3(256), 0, stream, result, cnt, cand);
    hipLaunchKernelGGL(k_final,   dim3(1),    dim3(1024), 0, stream, image, cnt, cand, out);
}